// Round 1
// baseline (192.432 us; speedup 1.0000x reference)
//
#include <hip/hip_runtime.h>
#include <math.h>

// Problem constants: input [32, 3, 512, 512] f32, output [32, 27, 512, 512] f32.
// Plane = 512*512 = 262144 pixels = 65536 float4 groups.
#define P4   65536          // float4 groups per channel plane
#define BATCH 32

__global__ __launch_bounds__(256) void sclayer_58746562675072_kernel(
        const float4* __restrict__ in, float4* __restrict__ out) {
    const int idx = blockIdx.x * blockDim.x + threadIdx.x;   // [0, BATCH*P4)
    const int b = idx >> 16;            // P4 == 2^16
    const int p = idx & (P4 - 1);

    const float4* inb = in + (size_t)b * (3 * P4) + p;
    float4 xv0 = inb[0 * P4];
    float4 xv1 = inb[1 * P4];
    float4 xv2 = inb[2 * P4];

    // base[c][k]: c = 0..2 raw, 3..5 cos, 6..8 sin; k = pixel within float4.
    float base[9][4];
    {
        const float xs[3][4] = {
            {xv0.x, xv0.y, xv0.z, xv0.w},
            {xv1.x, xv1.y, xv1.z, xv1.w},
            {xv2.x, xv2.y, xv2.z, xv2.w},
        };
        #pragma unroll
        for (int c = 0; c < 3; ++c) {
            #pragma unroll
            for (int k = 0; k < 4; ++k) {
                float x = xs[c][k];
                float s, co;
                __sincosf(x, &s, &co);
                base[c    ][k] = x;
                base[c + 3][k] = co;
                base[c + 6][k] = s;
            }
        }
    }

    float4* outb = out + (size_t)b * (27 * P4) + p;

    // Channels 0..8: the base values.
    #pragma unroll
    for (int c = 0; c < 9; ++c) {
        float4 v;
        v.x = base[c][0]; v.y = base[c][1]; v.z = base[c][2]; v.w = base[c][3];
        outb[c * P4] = v;
    }

    // Channels 9..26: the 18 pairwise products, in torch-loop order
    // (i in 0..8, j in range(i, 9, 3)).
    constexpr int II[18] = {0,0,0, 1,1,1, 2,2,2, 3,3, 4,4, 5,5, 6, 7, 8};
    constexpr int JJ[18] = {0,3,6, 1,4,7, 2,5,8, 3,6, 4,7, 5,8, 6, 7, 8};
    #pragma unroll
    for (int k = 0; k < 18; ++k) {
        float4 v;
        v.x = base[II[k]][0] * base[JJ[k]][0];
        v.y = base[II[k]][1] * base[JJ[k]][1];
        v.z = base[II[k]][2] * base[JJ[k]][2];
        v.w = base[II[k]][3] * base[JJ[k]][3];
        outb[(9 + k) * P4] = v;
    }
}

extern "C" void kernel_launch(void* const* d_in, const int* in_sizes, int n_in,
                              void* d_out, int out_size, void* d_ws, size_t ws_size,
                              hipStream_t stream) {
    const float4* in  = (const float4*)d_in[0];
    float4*       out = (float4*)d_out;
    const int total_threads = BATCH * P4;        // 2,097,152
    const int block = 256;
    const int grid  = total_threads / block;     // 8192
    sclayer_58746562675072_kernel<<<grid, block, 0, stream>>>(in, out);
}